// Round 8
// baseline (88.306 us; speedup 1.0000x reference)
//
#include <hip/hip_runtime.h>
#include <hip/hip_bf16.h>
#include <stdint.h>

#define GROUPS 256
#define SEQ    512
#define D_IN   128
#define D_QK   64
#define D_V    128
#define NTOK   (GROUPS * SEQ)

// scale * log2(e), folded into Wq/bq at prep time
#define SL2E (0.08838834764831845f * 1.4426950408889634f)

typedef short bf8 __attribute__((ext_vector_type(8)));
typedef short bf4 __attribute__((ext_vector_type(4)));
typedef float f32x4 __attribute__((ext_vector_type(4)));

__device__ __forceinline__ short f2bf(float f) {
    __bf16 h = (__bf16)f;
    return __builtin_bit_cast(short, h);
}

__device__ __forceinline__ void gload_lds16(const void* g, void* l) {
    __builtin_amdgcn_global_load_lds(
        (const __attribute__((address_space(1))) unsigned int*)(uintptr_t)(g),
        (__attribute__((address_space(3))) unsigned int*)(uint32_t)(uintptr_t)(l),
        16, 0, 0);
}

// ---------------------------------------------------------------------------
// Kernel 0: build PLAIN Wt bf16 [256 out-cols][128 k] row-major (256B rows)
// plus concatenated bias f32[256]. Q columns (r<64) pre-scaled by SL2E so
// QK^T emerges ready for exp2. Stashed in d_out's head (scratch).
// ---------------------------------------------------------------------------
__global__ __launch_bounds__(256) void prep_w(
    const float* __restrict__ Wq, const float* __restrict__ bq,
    const float* __restrict__ Wk, const float* __restrict__ bk,
    const float* __restrict__ Wv, const float* __restrict__ bv,
    short* __restrict__ Wt, float* __restrict__ bcat)
{
    const int t = blockIdx.x * 256 + threadIdx.x;   // 8192 threads
    const int r  = t >> 5;          // out col 0..255
    const int k0 = (t & 31) * 4;    // k 0..124
    const float* W; int ld; int c; float sc;
    if (r < 64)       { W = Wq; ld = 64;  c = r;       sc = SL2E; }
    else if (r < 128) { W = Wk; ld = 64;  c = r - 64;  sc = 1.0f; }
    else              { W = Wv; ld = 128; c = r - 128; sc = 1.0f; }
    bf4 pk;
#pragma unroll
    for (int i = 0; i < 4; ++i) pk[i] = f2bf(W[(size_t)(k0 + i) * ld + c] * sc);
    *reinterpret_cast<bf4*>(Wt + r * 128 + k0) = pk;
    if (t < 256) {
        const float* b = (t < 64) ? bq : (t < 128 ? bk : bv);
        const int cb   = (t < 64) ? t  : (t < 128 ? t - 64 : t - 128);
        bcat[t] = b[cb] * (t < 64 ? SL2E : 1.0f);
    }
}

// ---------------------------------------------------------------------------
// Kernel 1: MFMA projection v3. Block = 4 waves x 64 tokens; grid 2048.
// Wave w owns cf-quad {4w..4w+3}: wave0=Q, wave1=K, waves2-3=V. Its W
// fragments (16 x b128 from L2) live in 64 VGPR -- no W LDS, no per-cf loads.
// X (64 tok x 128 f32 = 32KB) staged to LDS via global_load_lds with
// chunk-XOR source pre-swizzle (chunk ^= tok&7, self-inverse) so the
// fp32 b128 reads hit the even-coverage bank floor.
// Q/K: C^T = mfma(W,X) -> lane owns token l15, cols lg*4+r -> 8B stores
//   (Q plain; K byte ^ ((tok&7)<<4)). V: C = mfma(X,W) -> lane owns d,
//   tokens lg*4+r -> 8B stores into pi+sd-swizzled Vt (round-7 image).
// ---------------------------------------------------------------------------
__global__ __launch_bounds__(256) void proj_kernel(
    const float* __restrict__ x, const short* __restrict__ Wt,
    const float* __restrict__ bcat,
    short* __restrict__ Q, short* __restrict__ K, short* __restrict__ Vt)
{
    __shared__ float xs[8192];      // 32KB: 64 tokens x 512B, chunk-swizzled
    const int tid = threadIdx.x;
    const int wid = tid >> 6, lane = tid & 63, l15 = lane & 15, lg = lane >> 4;
    const size_t tb = (size_t)blockIdx.x * 64;      // block token base
    const int g    = (int)(tb >> 9);
    const int tseg = (int)(tb & 511);               // multiple of 64

    // stage X: 8 instrs x (256 thr x 16B) = 32KB; source pre-swizzled so that
    // phys chunk c' = (tok<<5)|(lchunk ^ (tok&7)) holds logical (tok, lchunk).
#pragma unroll
    for (int i = 0; i < 8; ++i) {
        const int cph  = i * 256 + tid;             // physical 16B chunk
        const int tok  = cph >> 5;
        const int lchk = (cph & 31) ^ (tok & 7);
        gload_lds16((const char*)(x + (tb + tok) * D_IN) + lchk * 16,
                    (char*)xs + cph * 16);
    }

    // W fragments for this wave's cf-quad, straight from global (L2-hot)
    bf8 wf[4][4];
#pragma unroll
    for (int q = 0; q < 4; ++q) {
        const int cf = wid * 4 + q;
        const short* wr = Wt + (cf * 16 + l15) * 128 + lg * 8;
#pragma unroll
        for (int kf = 0; kf < 4; ++kf)
            wf[q][kf] = *reinterpret_cast<const bf8*>(wr + kf * 32);
    }
    __syncthreads();   // X staged (also drains W loads)

#pragma unroll
    for (int m = 0; m < 4; ++m) {
        const int tl = m * 16 + l15;                // block-local token
        const int sx = tl & 7;
        // X fragment: k = kf*32 + lg*8 + j, fp32 from swizzled LDS
        bf8 xfm[4];
#pragma unroll
        for (int kf = 0; kf < 4; ++kf) {
            const int c0 = (kf * 8 + lg * 2) ^ sx;
            const int c1 = (kf * 8 + lg * 2 + 1) ^ sx;
            const f32x4 a = *reinterpret_cast<const f32x4*>((const char*)xs + tl * 512 + c0 * 16);
            const f32x4 b = *reinterpret_cast<const f32x4*>((const char*)xs + tl * 512 + c1 * 16);
            bf8 v;
            v[0] = f2bf(a[0]); v[1] = f2bf(a[1]); v[2] = f2bf(a[2]); v[3] = f2bf(a[3]);
            v[4] = f2bf(b[0]); v[5] = f2bf(b[1]); v[6] = f2bf(b[2]); v[7] = f2bf(b[3]);
            xfm[kf] = v;
        }

        if (wid < 2) {
            // C^T = mfma(W, X): lane owns token tl, cols cf*16 + lg*4 + r
#pragma unroll
            for (int q = 0; q < 4; ++q) {
                const int cf = wid * 4 + q;
                f32x4 acc = (f32x4){0.f, 0.f, 0.f, 0.f};
#pragma unroll
                for (int kf = 0; kf < 4; ++kf)
                    acc = __builtin_amdgcn_mfma_f32_16x16x32_bf16(wf[q][kf], xfm[kf], acc, 0, 0, 0);
                const float4 bias4 = *reinterpret_cast<const float4*>(bcat + cf * 16 + lg * 4);
                bf4 pk;
                pk[0] = f2bf(acc[0] + bias4.x); pk[1] = f2bf(acc[1] + bias4.y);
                pk[2] = f2bf(acc[2] + bias4.z); pk[3] = f2bf(acc[3] + bias4.w);
                const size_t tok = tb + tl;
                if (wid == 0) {
                    *reinterpret_cast<bf4*>((char*)Q + tok * 128 + q * 32 + lg * 8) = pk;
                } else {
                    const int lo = (q * 32 + lg * 8) ^ (((int)tok & 7) << 4);
                    *reinterpret_cast<bf4*>((char*)K + tok * 128 + lo) = pk;
                }
            }
        } else {
            // C = mfma(X, W): lane owns col d = cf*16 + l15, tokens lg*4 + r
#pragma unroll
            for (int q = 0; q < 4; ++q) {
                const int cf = wid * 4 + q;         // 8..15
                f32x4 acc = (f32x4){0.f, 0.f, 0.f, 0.f};
#pragma unroll
                for (int kf = 0; kf < 4; ++kf)
                    acc = __builtin_amdgcn_mfma_f32_16x16x32_bf16(xfm[kf], wf[q][kf], acc, 0, 0, 0);
                const int d = (cf - 8) * 16 + l15;
                const float bias = bcat[cf * 16 + l15];
                bf4 pk;
#pragma unroll
                for (int r = 0; r < 4; ++r) pk[r] = f2bf(acc[r] + bias);
                const int t0   = tseg + m * 16;
                const int sd   = (d >> 1) & 3;
                const int phys = (t0 >> 5) * 64 + ((lg ^ sd) << 4) + ((t0 >> 4) & 1) * 8;
                *reinterpret_cast<bf4*>((char*)Vt + (((size_t)g * D_V + d) << 10) + phys) = pk;
            }
        }
    }
}

// ---------------------------------------------------------------------------
// Kernel 2: LDS-staged flash attention (round-7 version, unchanged).
// Block = 4 waves x 32 q-rows = 128 rows; grid (256 g, 4 rb) = 4 blocks/CU.
// KVBLK=32, 24KB LDS dbuf, stage-ahead-1 + single __syncthreads per tile.
// ---------------------------------------------------------------------------
__global__ __launch_bounds__(256, 4) void attn_kernel(
    const short* __restrict__ Q, const short* __restrict__ K,
    const short* __restrict__ Vt, float* __restrict__ out)
{
    __shared__ short lds[2 * 6144];   // per buf 12KB: K [0,4096)B, V [4096,12288)B
    const int g = blockIdx.x, rb = blockIdx.y;
    const int tid = threadIdx.x, wid = tid >> 6, lane = tid & 63;
    const int l15 = lane & 15, lg = lane >> 4;
    const size_t gtok = (size_t)g * SEQ;
    const int row0 = rb * 128 + wid * 32;

    bf8 qf[2][2];
#pragma unroll
    for (int rf = 0; rf < 2; ++rf) {
        const short* qr = Q + (gtok + row0 + rf * 16 + l15) * 64 + lg * 8;
        qf[rf][0] = *reinterpret_cast<const bf8*>(qr);
        qf[rf][1] = *reinterpret_cast<const bf8*>(qr + 32);
    }

    const char* Kg = (const char*)(K + gtok * 64);
    const char* Vg = (const char*)(Vt + ((size_t)g * D_V << 9));

    f32x4 o[2][8];
#pragma unroll
    for (int rf = 0; rf < 2; ++rf)
#pragma unroll
        for (int vt = 0; vt < 8; ++vt) o[rf][vt] = (f32x4){0.f, 0.f, 0.f, 0.f};
    f32x4 psv[2] = {(f32x4){0.f, 0.f, 0.f, 0.f}, (f32x4){0.f, 0.f, 0.f, 0.f}};
    const bf8 onesf = {0x3F80, 0x3F80, 0x3F80, 0x3F80, 0x3F80, 0x3F80, 0x3F80, 0x3F80};

    auto stage = [&](int kt, int b) {
        char* lbase = (char*)lds + b * 12288;
        int c = wid * 3;
#pragma unroll
        for (int i = 0; i < 3; ++i, ++c) {
            if (c < 4) {
                gload_lds16(Kg + (size_t)kt * 4096 + c * 1024 + lane * 16,
                            lbase + c * 1024 + lane * 16);
            } else {
                const int cv = c - 4;
                const int d  = cv * 16 + (lane >> 2);
                gload_lds16(Vg + (size_t)d * 1024 + kt * 64 + (lane & 3) * 16,
                            lbase + 4096 + cv * 1024 + lane * 16);
            }
        }
    };

    auto compute = [&](int b) {
        const char* lb = (const char*)lds + b * 12288;
        f32x4 st[2][2];
#pragma unroll
        for (int tf = 0; tf < 2; ++tf) {
            const int tok = tf * 16 + l15;
            const char* kb = lb + tok * 128;
            const int x7 = (tok & 7) << 4;
            const bf8 k0 = *reinterpret_cast<const bf8*>(kb + ((lg * 16) ^ x7));
            const bf8 k1 = *reinterpret_cast<const bf8*>(kb + ((64 + lg * 16) ^ x7));
#pragma unroll
            for (int rf = 0; rf < 2; ++rf) {
                f32x4 s = (f32x4){0.f, 0.f, 0.f, 0.f};
                s = __builtin_amdgcn_mfma_f32_16x16x32_bf16(k0, qf[rf][0], s, 0, 0, 0);
                s = __builtin_amdgcn_mfma_f32_16x16x32_bf16(k1, qf[rf][1], s, 0, 0, 0);
                st[tf][rf] = s;
            }
        }
        bf8 pa[2];
#pragma unroll
        for (int rf = 0; rf < 2; ++rf) {
            bf8 pv;
#pragma unroll
            for (int i = 0; i < 4; ++i) {
                pv[i]     = f2bf(__builtin_amdgcn_exp2f(st[0][rf][i]));
                pv[i + 4] = f2bf(__builtin_amdgcn_exp2f(st[1][rf][i]));
            }
            pa[rf] = pv;
            psv[rf] = __builtin_amdgcn_mfma_f32_16x16x32_bf16(pv, onesf, psv[rf], 0, 0, 0);
        }
        const char* vb = lb + 4096;
#pragma unroll
        for (int vt = 0; vt < 8; ++vt) {
            const int d = vt * 16 + l15;
            const char* vr = vb + d * 64;
            const bf8 v0 = *reinterpret_cast<const bf8*>(vr + ((lg * 16) ^ ((((d >> 1) & 3)) << 4)));
            o[0][vt] = __builtin_amdgcn_mfma_f32_16x16x32_bf16(pa[0], v0, o[0][vt], 0, 0, 0);
            o[1][vt] = __builtin_amdgcn_mfma_f32_16x16x32_bf16(pa[1], v0, o[1][vt], 0, 0, 0);
        }
    };

    stage(0, 0);
    __syncthreads();
    for (int kt = 0; kt < 16; ++kt) {
        const int b = kt & 1;
        if (kt < 15) stage(kt + 1, b ^ 1);
        compute(b);
        __syncthreads();
    }

#pragma unroll
    for (int rf = 0; rf < 2; ++rf) {
        float linv[4];
#pragma unroll
        for (int r = 0; r < 4; ++r) linv[r] = 1.0f / psv[rf][r];
        float* op = out + (gtok + row0 + rf * 16) * D_V;
#pragma unroll
        for (int vt = 0; vt < 8; ++vt)
#pragma unroll
            for (int r = 0; r < 4; ++r)
                op[(size_t)(lg * 4 + r) * D_V + vt * 16 + l15] = o[rf][vt][r] * linv[r];
    }
}

extern "C" void kernel_launch(void* const* d_in, const int* in_sizes, int n_in,
                              void* d_out, int out_size, void* d_ws, size_t ws_size,
                              hipStream_t stream) {
    (void)in_sizes; (void)n_in; (void)ws_size; (void)out_size;
    const float* x  = (const float*)d_in[0];
    // d_in[1] = index (int64) -- fixed equal-length sorted groups; unused.
    const float* Wq = (const float*)d_in[2];
    const float* bq = (const float*)d_in[3];
    const float* Wk = (const float*)d_in[4];
    const float* bk = (const float*)d_in[5];
    const float* Wv = (const float*)d_in[6];
    const float* bv = (const float*)d_in[7];
    float* out = (float*)d_out;

    short* Qw = (short*)d_ws;                       // [NTOK][64] bf16
    short* Kw = Qw + (size_t)NTOK * D_QK;           // [NTOK][64] bf16 (chunk-swizzled rows)
    short* Vt = Kw + (size_t)NTOK * D_QK;           // [GROUPS][128][512] bf16 (pi+swizzled)

    short* Wt   = (short*)out;                      // scratch in d_out head
    float* bcat = (float*)((char*)out + 65536);

    prep_w<<<32, 256, 0, stream>>>(Wq, bq, Wk, bk, Wv, bv, Wt, bcat);
    proj_kernel<<<NTOK / 64, 256, 0, stream>>>(x, Wt, bcat, Qw, Kw, Vt);
    attn_kernel<<<dim3(GROUPS, 4), 256, 0, stream>>>(Qw, Kw, Vt, out);
}

// Round 9
// 81.334 us; speedup vs baseline: 1.0857x; 1.0857x over previous
//
#include <hip/hip_runtime.h>
#include <hip/hip_bf16.h>
#include <stdint.h>

#define GROUPS 256
#define SEQ    512
#define D_IN   128
#define D_QK   64
#define D_V    128
#define NTOK   (GROUPS * SEQ)

// scale * log2(e), folded into Wq/bq at prep time
#define SL2E (0.08838834764831845f * 1.4426950408889634f)

typedef short bf8 __attribute__((ext_vector_type(8)));
typedef short bf4 __attribute__((ext_vector_type(4)));
typedef float f32x4 __attribute__((ext_vector_type(4)));

__device__ __forceinline__ short f2bf(float f) {
    __bf16 h = (__bf16)f;
    return __builtin_bit_cast(short, h);
}

__device__ __forceinline__ void gload_lds16(const void* g, void* l) {
    __builtin_amdgcn_global_load_lds(
        (const __attribute__((address_space(1))) unsigned int*)(uintptr_t)(g),
        (__attribute__((address_space(3))) unsigned int*)(uint32_t)(uintptr_t)(l),
        16, 0, 0);
}

// ---------------------------------------------------------------------------
// Kernel 0: build Wt bf16 [256 out-cols][128 k], XOR-swizzled image
// (8B chunk at logical byte b in a 256B row stored at b ^ ((row&7)<<4)),
// plus concatenated bias f32[256]. Q columns (r<64) pre-scaled by SL2E so
// QK^T emerges ready for exp2. Stashed in d_out's head (scratch).
// ---------------------------------------------------------------------------
__global__ __launch_bounds__(256) void prep_w(
    const float* __restrict__ Wq, const float* __restrict__ bq,
    const float* __restrict__ Wk, const float* __restrict__ bk,
    const float* __restrict__ Wv, const float* __restrict__ bv,
    short* __restrict__ Wt, float* __restrict__ bcat)
{
    const int t = blockIdx.x * 256 + threadIdx.x;   // 8192 threads
    const int r  = t >> 5;          // out col 0..255
    const int k0 = (t & 31) * 4;    // k 0..124
    const float* W; int ld; int c; float sc;
    if (r < 64)       { W = Wq; ld = 64;  c = r;       sc = SL2E; }
    else if (r < 128) { W = Wk; ld = 64;  c = r - 64;  sc = 1.0f; }
    else              { W = Wv; ld = 128; c = r - 128; sc = 1.0f; }
    bf4 pk;
#pragma unroll
    for (int i = 0; i < 4; ++i) pk[i] = f2bf(W[(size_t)(k0 + i) * ld + c] * sc);
    const int phys = (k0 * 2) ^ ((r & 7) << 4);     // swizzled byte offset in row
    *reinterpret_cast<bf4*>((char*)Wt + r * 256 + phys) = pk;
    if (t < 256) {
        const float* b = (t < 64) ? bq : (t < 128 ? bk : bv);
        const int cb   = (t < 64) ? t  : (t < 128 ? t - 64 : t - 128);
        bcat[t] = b[cb] * (t < 64 ? SL2E : 1.0f);
    }
}

// ---------------------------------------------------------------------------
// Kernel 1: MFMA projection, ROLE-SPLIT for occupancy. Grid (512, 2):
// blockIdx.y==0 -> Q|K half (stages Wt rows 0-127, 32KB LDS);
// blockIdx.y==1 -> V half   (stages Wt rows 128-255, 32KB LDS).
// 32KB LDS + ~90 VGPR -> 4 blocks/CU (vs 2 with the 64KB monolith).
// Inner code per cf identical to the round-4/7 validated version:
// Q/K: C^T = mfma(W, X) -> lane owns token, cols lg*4+r -> 8B packed stores
//   (Q plain; K byte ^ ((tok&7)<<4)). V: C = mfma(X, W) -> lane owns d,
//   tokens lg*4+r -> 8B stores into pi+sd-swizzled Vt (round-7 image).
// ---------------------------------------------------------------------------
__global__ __launch_bounds__(256) void proj_kernel(
    const float* __restrict__ x, const short* __restrict__ Wt,
    const float* __restrict__ bcat,
    short* __restrict__ Q, short* __restrict__ K, short* __restrict__ Vt)
{
    __shared__ short wlds[16384];   // 32KB: this role's swizzled W half-image
    const int tid  = threadIdx.x;
    const int role = blockIdx.y;    // 0 = Q|K, 1 = V
    const int wid = tid >> 6, lane = tid & 63, l15 = lane & 15, lg = lane >> 4;

    // stage this role's W half: 8 x (256 thr x 16B) = 32KB, linear
#pragma unroll
    for (int i = 0; i < 8; ++i)
        gload_lds16((const char*)Wt + role * 32768 + i * 4096 + tid * 16,
                    (char*)wlds + i * 4096 + tid * 16);

    const size_t tw = (size_t)blockIdx.x * 256 + wid * 64;   // wave token base
    const int g     = (int)(tw >> 9);
    const int tseg  = (int)(tw & 511);                        // multiple of 64

    bf8 xf[4][4];
#pragma unroll
    for (int m = 0; m < 4; ++m) {
        const float* xr = x + (tw + m * 16 + l15) * D_IN;
#pragma unroll
        for (int kf = 0; kf < 4; ++kf) {
            const float4 a = *reinterpret_cast<const float4*>(xr + kf * 32 + lg * 8);
            const float4 b = *reinterpret_cast<const float4*>(xr + kf * 32 + lg * 8 + 4);
            bf8 v;
            v[0] = f2bf(a.x); v[1] = f2bf(a.y); v[2] = f2bf(a.z); v[3] = f2bf(a.w);
            v[4] = f2bf(b.x); v[5] = f2bf(b.y); v[6] = f2bf(b.z); v[7] = f2bf(b.w);
            xf[m][kf] = v;
        }
    }
    __syncthreads();   // W staged

#pragma unroll
    for (int cf = 0; cf < 8; ++cf) {            // local cf within role
        const int lrow = cf * 16 + l15;         // row in this role's half-image
        const int acf  = role * 8 + cf;         // global cf (bias index)
        bf8 wf[4];
#pragma unroll
        for (int kf = 0; kf < 4; ++kf) {
            const int off = (kf * 64 + lg * 16) ^ ((lrow & 7) << 4);
            wf[kf] = *reinterpret_cast<const bf8*>((const char*)wlds + lrow * 256 + off);
        }

        if (role == 0) {
            const float4 bias4 = *reinterpret_cast<const float4*>(bcat + acf * 16 + lg * 4);
#pragma unroll
            for (int m = 0; m < 4; ++m) {
                f32x4 acc = (f32x4){0.f, 0.f, 0.f, 0.f};
#pragma unroll
                for (int kf = 0; kf < 4; ++kf)
                    acc = __builtin_amdgcn_mfma_f32_16x16x32_bf16(wf[kf], xf[m][kf], acc, 0, 0, 0);
                bf4 pk;
                pk[0] = f2bf(acc[0] + bias4.x); pk[1] = f2bf(acc[1] + bias4.y);
                pk[2] = f2bf(acc[2] + bias4.z); pk[3] = f2bf(acc[3] + bias4.w);
                const size_t tok = tw + m * 16 + l15;
                if (cf < 4) {
                    *reinterpret_cast<bf4*>((char*)Q + tok * 128 + cf * 32 + lg * 8) = pk;
                } else {
                    const int lo = ((cf - 4) * 32 + lg * 8) ^ (((int)tok & 7) << 4);
                    *reinterpret_cast<bf4*>((char*)K + tok * 128 + lo) = pk;
                }
            }
        } else {
            const int d = cf * 16 + l15;
            const float bias = bcat[acf * 16 + l15];
            char* vrow = (char*)Vt + (((size_t)g * D_V + d) << 10);
            const int sd = (d >> 1) & 3;
#pragma unroll
            for (int m = 0; m < 4; ++m) {
                f32x4 acc = (f32x4){0.f, 0.f, 0.f, 0.f};
#pragma unroll
                for (int kf = 0; kf < 4; ++kf)
                    acc = __builtin_amdgcn_mfma_f32_16x16x32_bf16(xf[m][kf], wf[kf], acc, 0, 0, 0);
                bf4 pk;
#pragma unroll
                for (int r = 0; r < 4; ++r) pk[r] = f2bf(acc[r] + bias);
                const int t0   = tseg + m * 16;
                const int phys = (t0 >> 5) * 64 + ((lg ^ sd) << 4) + ((t0 >> 4) & 1) * 8;
                *reinterpret_cast<bf4*>(vrow + phys) = pk;
            }
        }
    }
}

// ---------------------------------------------------------------------------
// Kernel 2: LDS-staged flash attention (round-7 skeleton, + T5 setprio).
// Block = 4 waves x 32 q-rows = 128 rows; grid (256 g, 4 rb) = 4 blocks/CU.
// KVBLK=32, 24KB LDS dbuf, stage-ahead-1 + single __syncthreads per tile.
// ---------------------------------------------------------------------------
__global__ __launch_bounds__(256, 4) void attn_kernel(
    const short* __restrict__ Q, const short* __restrict__ K,
    const short* __restrict__ Vt, float* __restrict__ out)
{
    __shared__ short lds[2 * 6144];   // per buf 12KB: K [0,4096)B, V [4096,12288)B
    const int g = blockIdx.x, rb = blockIdx.y;
    const int tid = threadIdx.x, wid = tid >> 6, lane = tid & 63;
    const int l15 = lane & 15, lg = lane >> 4;
    const size_t gtok = (size_t)g * SEQ;
    const int row0 = rb * 128 + wid * 32;

    bf8 qf[2][2];
#pragma unroll
    for (int rf = 0; rf < 2; ++rf) {
        const short* qr = Q + (gtok + row0 + rf * 16 + l15) * 64 + lg * 8;
        qf[rf][0] = *reinterpret_cast<const bf8*>(qr);
        qf[rf][1] = *reinterpret_cast<const bf8*>(qr + 32);
    }

    const char* Kg = (const char*)(K + gtok * 64);
    const char* Vg = (const char*)(Vt + ((size_t)g * D_V << 9));

    f32x4 o[2][8];
#pragma unroll
    for (int rf = 0; rf < 2; ++rf)
#pragma unroll
        for (int vt = 0; vt < 8; ++vt) o[rf][vt] = (f32x4){0.f, 0.f, 0.f, 0.f};
    f32x4 psv[2] = {(f32x4){0.f, 0.f, 0.f, 0.f}, (f32x4){0.f, 0.f, 0.f, 0.f}};
    const bf8 onesf = {0x3F80, 0x3F80, 0x3F80, 0x3F80, 0x3F80, 0x3F80, 0x3F80, 0x3F80};

    auto stage = [&](int kt, int b) {
        char* lbase = (char*)lds + b * 12288;
        int c = wid * 3;
#pragma unroll
        for (int i = 0; i < 3; ++i, ++c) {
            if (c < 4) {
                gload_lds16(Kg + (size_t)kt * 4096 + c * 1024 + lane * 16,
                            lbase + c * 1024 + lane * 16);
            } else {
                const int cv = c - 4;
                const int d  = cv * 16 + (lane >> 2);
                gload_lds16(Vg + (size_t)d * 1024 + kt * 64 + (lane & 3) * 16,
                            lbase + 4096 + cv * 1024 + lane * 16);
            }
        }
    };

    auto compute = [&](int b) {
        const char* lb = (const char*)lds + b * 12288;
        __builtin_amdgcn_s_setprio(1);
        f32x4 st[2][2];
#pragma unroll
        for (int tf = 0; tf < 2; ++tf) {
            const int tok = tf * 16 + l15;
            const char* kb = lb + tok * 128;
            const int x7 = (tok & 7) << 4;
            const bf8 k0 = *reinterpret_cast<const bf8*>(kb + ((lg * 16) ^ x7));
            const bf8 k1 = *reinterpret_cast<const bf8*>(kb + ((64 + lg * 16) ^ x7));
#pragma unroll
            for (int rf = 0; rf < 2; ++rf) {
                f32x4 s = (f32x4){0.f, 0.f, 0.f, 0.f};
                s = __builtin_amdgcn_mfma_f32_16x16x32_bf16(k0, qf[rf][0], s, 0, 0, 0);
                s = __builtin_amdgcn_mfma_f32_16x16x32_bf16(k1, qf[rf][1], s, 0, 0, 0);
                st[tf][rf] = s;
            }
        }
        bf8 pa[2];
#pragma unroll
        for (int rf = 0; rf < 2; ++rf) {
            bf8 pv;
#pragma unroll
            for (int i = 0; i < 4; ++i) {
                pv[i]     = f2bf(__builtin_amdgcn_exp2f(st[0][rf][i]));
                pv[i + 4] = f2bf(__builtin_amdgcn_exp2f(st[1][rf][i]));
            }
            pa[rf] = pv;
            psv[rf] = __builtin_amdgcn_mfma_f32_16x16x32_bf16(pv, onesf, psv[rf], 0, 0, 0);
        }
        const char* vb = lb + 4096;
#pragma unroll
        for (int vt = 0; vt < 8; ++vt) {
            const int d = vt * 16 + l15;
            const char* vr = vb + d * 64;
            const bf8 v0 = *reinterpret_cast<const bf8*>(vr + ((lg * 16) ^ ((((d >> 1) & 3)) << 4)));
            o[0][vt] = __builtin_amdgcn_mfma_f32_16x16x32_bf16(pa[0], v0, o[0][vt], 0, 0, 0);
            o[1][vt] = __builtin_amdgcn_mfma_f32_16x16x32_bf16(pa[1], v0, o[1][vt], 0, 0, 0);
        }
        __builtin_amdgcn_s_setprio(0);
    };

    stage(0, 0);
    __syncthreads();
    for (int kt = 0; kt < 16; ++kt) {
        const int b = kt & 1;
        if (kt < 15) stage(kt + 1, b ^ 1);
        compute(b);
        __syncthreads();
    }

#pragma unroll
    for (int rf = 0; rf < 2; ++rf) {
        float linv[4];
#pragma unroll
        for (int r = 0; r < 4; ++r) linv[r] = 1.0f / psv[rf][r];
        float* op = out + (gtok + row0 + rf * 16) * D_V;
#pragma unroll
        for (int vt = 0; vt < 8; ++vt)
#pragma unroll
            for (int r = 0; r < 4; ++r)
                op[(size_t)(lg * 4 + r) * D_V + vt * 16 + l15] = o[rf][vt][r] * linv[r];
    }
}

extern "C" void kernel_launch(void* const* d_in, const int* in_sizes, int n_in,
                              void* d_out, int out_size, void* d_ws, size_t ws_size,
                              hipStream_t stream) {
    (void)in_sizes; (void)n_in; (void)ws_size; (void)out_size;
    const float* x  = (const float*)d_in[0];
    // d_in[1] = index (int64) -- fixed equal-length sorted groups; unused.
    const float* Wq = (const float*)d_in[2];
    const float* bq = (const float*)d_in[3];
    const float* Wk = (const float*)d_in[4];
    const float* bk = (const float*)d_in[5];
    const float* Wv = (const float*)d_in[6];
    const float* bv = (const float*)d_in[7];
    float* out = (float*)d_out;

    short* Qw = (short*)d_ws;                       // [NTOK][64] bf16
    short* Kw = Qw + (size_t)NTOK * D_QK;           // [NTOK][64] bf16 (chunk-swizzled rows)
    short* Vt = Kw + (size_t)NTOK * D_QK;           // [GROUPS][128][512] bf16 (pi+swizzled)

    short* Wt   = (short*)out;                      // scratch in d_out head
    float* bcat = (float*)((char*)out + 65536);

    prep_w<<<32, 256, 0, stream>>>(Wq, bq, Wk, bk, Wv, bv, Wt, bcat);
    proj_kernel<<<dim3(NTOK / 256, 2), 256, 0, stream>>>(x, Wt, bcat, Qw, Kw, Vt);
    attn_kernel<<<dim3(GROUPS, 4), 256, 0, stream>>>(Qw, Kw, Vt, out);
}

// Round 10
// 67.952 us; speedup vs baseline: 1.2995x; 1.1969x over previous
//
#include <hip/hip_runtime.h>
#include <hip/hip_bf16.h>
#include <stdint.h>

#define GROUPS 256
#define SEQ    512
#define D_IN   128
#define D_QK   64
#define D_V    128
#define NTOK   (GROUPS * SEQ)

// scale * log2(e), folded into Wq/bq at prep time
#define SL2E (0.08838834764831845f * 1.4426950408889634f)

typedef short bf8 __attribute__((ext_vector_type(8)));
typedef short bf4 __attribute__((ext_vector_type(4)));
typedef float f32x4 __attribute__((ext_vector_type(4)));

__device__ __forceinline__ short f2bf(float f) {
    __bf16 h = (__bf16)f;
    return __builtin_bit_cast(short, h);
}

__device__ __forceinline__ void gload_lds16(const void* g, void* l) {
    __builtin_amdgcn_global_load_lds(
        (const __attribute__((address_space(1))) unsigned int*)(uintptr_t)(g),
        (__attribute__((address_space(3))) unsigned int*)(uint32_t)(uintptr_t)(l),
        16, 0, 0);
}

// ---------------------------------------------------------------------------
// Kernel 0: build Wt bf16 [256 out-cols][128 k], XOR-swizzled image
// (8B chunk at logical byte b in a 256B row stored at b ^ ((row&7)<<4)),
// plus concatenated bias f32[256]. Q columns (r<64) pre-scaled by SL2E so
// QK^T emerges ready for exp2. Stashed in d_out's head (scratch).
// ---------------------------------------------------------------------------
__global__ __launch_bounds__(256) void prep_w(
    const float* __restrict__ Wq, const float* __restrict__ bq,
    const float* __restrict__ Wk, const float* __restrict__ bk,
    const float* __restrict__ Wv, const float* __restrict__ bv,
    short* __restrict__ Wt, float* __restrict__ bcat)
{
    const int t = blockIdx.x * 256 + threadIdx.x;   // 8192 threads
    const int r  = t >> 5;          // out col 0..255
    const int k0 = (t & 31) * 4;    // k 0..124
    const float* W; int ld; int c; float sc;
    if (r < 64)       { W = Wq; ld = 64;  c = r;       sc = SL2E; }
    else if (r < 128) { W = Wk; ld = 64;  c = r - 64;  sc = 1.0f; }
    else              { W = Wv; ld = 128; c = r - 128; sc = 1.0f; }
    bf4 pk;
#pragma unroll
    for (int i = 0; i < 4; ++i) pk[i] = f2bf(W[(size_t)(k0 + i) * ld + c] * sc);
    const int phys = (k0 * 2) ^ ((r & 7) << 4);     // swizzled byte offset in row
    *reinterpret_cast<bf4*>((char*)Wt + r * 256 + phys) = pk;
    if (t < 256) {
        const float* b = (t < 64) ? bq : (t < 128 ? bk : bv);
        const int cb   = (t < 64) ? t  : (t < 128 ? t - 64 : t - 128);
        bcat[t] = b[cb] * (t < 64 ? SL2E : 1.0f);
    }
}

// ---------------------------------------------------------------------------
// Kernel 1: MFMA projection (round-7 monolith, best measured). Block = 4 waves
// x 64 tokens = 256 tokens; grid 512. W (64KB swizzled) staged once into LDS.
// Q/K: C^T = mfma(W, X) -> 8B packed stores (Q plain; K byte ^ ((tok&7)<<4)).
// V:   C = mfma(X, W)   -> 8B packed stores into TILE-MAJOR Vt:
//   Vt byte addr = g*131072 + (tok>>5)*8192 + d*64 + (chunk swizzle within 64B)
//   so each 32-token tile's V is one contiguous 8KB block (linear attn stage).
// ---------------------------------------------------------------------------
__global__ __launch_bounds__(256) void proj_kernel(
    const float* __restrict__ x, const short* __restrict__ Wt,
    const float* __restrict__ bcat,
    short* __restrict__ Q, short* __restrict__ K, short* __restrict__ Vt)
{
    __shared__ short wlds[32768];   // 64KB swizzled W image
    const int tid = threadIdx.x;
    const int wid = tid >> 6, lane = tid & 63, l15 = lane & 15, lg = lane >> 4;

#pragma unroll
    for (int i = 0; i < 16; ++i)
        gload_lds16((const char*)Wt + i * 4096 + tid * 16,
                    (char*)wlds + i * 4096 + tid * 16);

    const size_t tw = (size_t)blockIdx.x * 256 + wid * 64;   // wave token base
    const int g     = (int)(tw >> 9);
    const int tseg  = (int)(tw & 511);                        // multiple of 64

    bf8 xf[4][4];
#pragma unroll
    for (int m = 0; m < 4; ++m) {
        const float* xr = x + (tw + m * 16 + l15) * D_IN;
#pragma unroll
        for (int kf = 0; kf < 4; ++kf) {
            const float4 a = *reinterpret_cast<const float4*>(xr + kf * 32 + lg * 8);
            const float4 b = *reinterpret_cast<const float4*>(xr + kf * 32 + lg * 8 + 4);
            bf8 v;
            v[0] = f2bf(a.x); v[1] = f2bf(a.y); v[2] = f2bf(a.z); v[3] = f2bf(a.w);
            v[4] = f2bf(b.x); v[5] = f2bf(b.y); v[6] = f2bf(b.z); v[7] = f2bf(b.w);
            xf[m][kf] = v;
        }
    }
    __syncthreads();   // W staged

#pragma unroll
    for (int cf = 0; cf < 16; ++cf) {
        const int wrow = cf * 16 + l15;
        bf8 wf[4];
#pragma unroll
        for (int kf = 0; kf < 4; ++kf) {
            const int off = (kf * 64 + lg * 16) ^ ((wrow & 7) << 4);
            wf[kf] = *reinterpret_cast<const bf8*>((const char*)wlds + wrow * 256 + off);
        }

        if (cf < 8) {
            const float4 bias4 = *reinterpret_cast<const float4*>(bcat + cf * 16 + lg * 4);
#pragma unroll
            for (int m = 0; m < 4; ++m) {
                f32x4 acc = (f32x4){0.f, 0.f, 0.f, 0.f};
#pragma unroll
                for (int kf = 0; kf < 4; ++kf)
                    acc = __builtin_amdgcn_mfma_f32_16x16x32_bf16(wf[kf], xf[m][kf], acc, 0, 0, 0);
                bf4 pk;
                pk[0] = f2bf(acc[0] + bias4.x); pk[1] = f2bf(acc[1] + bias4.y);
                pk[2] = f2bf(acc[2] + bias4.z); pk[3] = f2bf(acc[3] + bias4.w);
                const size_t tok = tw + m * 16 + l15;
                if (cf < 4) {
                    *reinterpret_cast<bf4*>((char*)Q + tok * 128 + cf * 32 + lg * 8) = pk;
                } else {
                    const int lo = ((cf - 4) * 32 + lg * 8) ^ (((int)tok & 7) << 4);
                    *reinterpret_cast<bf4*>((char*)K + tok * 128 + lo) = pk;
                }
            }
        } else {
            const int d = (cf - 8) * 16 + l15;
            const float bias = bcat[cf * 16 + l15];
            const int sd = (d >> 1) & 3;
            char* vg = (char*)Vt + (size_t)g * 131072 + (size_t)d * 64;
#pragma unroll
            for (int m = 0; m < 4; ++m) {
                f32x4 acc = (f32x4){0.f, 0.f, 0.f, 0.f};
#pragma unroll
                for (int kf = 0; kf < 4; ++kf)
                    acc = __builtin_amdgcn_mfma_f32_16x16x32_bf16(xf[m][kf], wf[kf], acc, 0, 0, 0);
                bf4 pk;
#pragma unroll
                for (int r = 0; r < 4; ++r) pk[r] = f2bf(acc[r] + bias);
                const int t0    = tseg + m * 16;
                const int inner = ((lg ^ sd) << 4) + ((t0 >> 4) & 1) * 8;
                *reinterpret_cast<bf4*>(vg + (size_t)(t0 >> 5) * 8192 + inner) = pk;
            }
        }
    }
}

// ---------------------------------------------------------------------------
// Kernel 2: LDS-staged flash attention (round-7 skeleton, unchanged math).
// Block = 4 waves x 32 q-rows = 128 rows; grid (256 g, 4 rb) = 4 blocks/CU.
// KVBLK=32, 24KB LDS dbuf, stage-ahead-1 + single __syncthreads per tile.
// ONLY change vs r7: V staged from the tile-major contiguous layout
// (linear 1KB gload_lds chunks, no 16-way scatter-gather).
// ---------------------------------------------------------------------------
__global__ __launch_bounds__(256, 4) void attn_kernel(
    const short* __restrict__ Q, const short* __restrict__ K,
    const short* __restrict__ Vt, float* __restrict__ out)
{
    __shared__ short lds[2 * 6144];   // per buf 12KB: K [0,4096)B, V [4096,12288)B
    const int g = blockIdx.x, rb = blockIdx.y;
    const int tid = threadIdx.x, wid = tid >> 6, lane = tid & 63;
    const int l15 = lane & 15, lg = lane >> 4;
    const size_t gtok = (size_t)g * SEQ;
    const int row0 = rb * 128 + wid * 32;

    bf8 qf[2][2];
#pragma unroll
    for (int rf = 0; rf < 2; ++rf) {
        const short* qr = Q + (gtok + row0 + rf * 16 + l15) * 64 + lg * 8;
        qf[rf][0] = *reinterpret_cast<const bf8*>(qr);
        qf[rf][1] = *reinterpret_cast<const bf8*>(qr + 32);
    }

    const char* Kg = (const char*)(K + gtok * 64);
    const char* Vg = (const char*)Vt + (size_t)g * 131072;   // tile-major V

    f32x4 o[2][8];
#pragma unroll
    for (int rf = 0; rf < 2; ++rf)
#pragma unroll
        for (int vt = 0; vt < 8; ++vt) o[rf][vt] = (f32x4){0.f, 0.f, 0.f, 0.f};
    f32x4 psv[2] = {(f32x4){0.f, 0.f, 0.f, 0.f}, (f32x4){0.f, 0.f, 0.f, 0.f}};
    const bf8 onesf = {0x3F80, 0x3F80, 0x3F80, 0x3F80, 0x3F80, 0x3F80, 0x3F80, 0x3F80};

    // stage tile kt (32 tokens): 12 x 1KB LINEAR chunks, 3 per wave.
    // K tile: 4KB contiguous (chunks 0-3). V tile: 8KB contiguous (chunks 4-11).
    auto stage = [&](int kt, int b) {
        char* lbase = (char*)lds + b * 12288;
        int c = wid * 3;
#pragma unroll
        for (int i = 0; i < 3; ++i, ++c) {
            if (c < 4) {
                gload_lds16(Kg + (size_t)kt * 4096 + c * 1024 + lane * 16,
                            lbase + c * 1024 + lane * 16);
            } else {
                gload_lds16(Vg + (size_t)kt * 8192 + (c - 4) * 1024 + lane * 16,
                            lbase + c * 1024 + lane * 16);
            }
        }
    };

    auto compute = [&](int b) {
        const char* lb = (const char*)lds + b * 12288;
        f32x4 st[2][2];
#pragma unroll
        for (int tf = 0; tf < 2; ++tf) {
            const int tok = tf * 16 + l15;
            const char* kb = lb + tok * 128;
            const int x7 = (tok & 7) << 4;
            const bf8 k0 = *reinterpret_cast<const bf8*>(kb + ((lg * 16) ^ x7));
            const bf8 k1 = *reinterpret_cast<const bf8*>(kb + ((64 + lg * 16) ^ x7));
#pragma unroll
            for (int rf = 0; rf < 2; ++rf) {
                f32x4 s = (f32x4){0.f, 0.f, 0.f, 0.f};
                s = __builtin_amdgcn_mfma_f32_16x16x32_bf16(k0, qf[rf][0], s, 0, 0, 0);
                s = __builtin_amdgcn_mfma_f32_16x16x32_bf16(k1, qf[rf][1], s, 0, 0, 0);
                st[tf][rf] = s;
            }
        }
        bf8 pa[2];
#pragma unroll
        for (int rf = 0; rf < 2; ++rf) {
            bf8 pv;
#pragma unroll
            for (int i = 0; i < 4; ++i) {
                pv[i]     = f2bf(__builtin_amdgcn_exp2f(st[0][rf][i]));
                pv[i + 4] = f2bf(__builtin_amdgcn_exp2f(st[1][rf][i]));
            }
            pa[rf] = pv;
            psv[rf] = __builtin_amdgcn_mfma_f32_16x16x32_bf16(pv, onesf, psv[rf], 0, 0, 0);
        }
        const char* vb = lb + 4096;
#pragma unroll
        for (int vt = 0; vt < 8; ++vt) {
            const int d = vt * 16 + l15;
            const char* vr = vb + d * 64;
            const bf8 v0 = *reinterpret_cast<const bf8*>(vr + ((lg * 16) ^ ((((d >> 1) & 3)) << 4)));
            o[0][vt] = __builtin_amdgcn_mfma_f32_16x16x32_bf16(pa[0], v0, o[0][vt], 0, 0, 0);
            o[1][vt] = __builtin_amdgcn_mfma_f32_16x16x32_bf16(pa[1], v0, o[1][vt], 0, 0, 0);
        }
    };

    stage(0, 0);
    __syncthreads();
    for (int kt = 0; kt < 16; ++kt) {
        const int b = kt & 1;
        if (kt < 15) stage(kt + 1, b ^ 1);
        compute(b);
        __syncthreads();
    }

#pragma unroll
    for (int rf = 0; rf < 2; ++rf) {
        float linv[4];
#pragma unroll
        for (int r = 0; r < 4; ++r) linv[r] = 1.0f / psv[rf][r];
        float* op = out + (gtok + row0 + rf * 16) * D_V;
#pragma unroll
        for (int vt = 0; vt < 8; ++vt)
#pragma unroll
            for (int r = 0; r < 4; ++r)
                op[(size_t)(lg * 4 + r) * D_V + vt * 16 + l15] = o[rf][vt][r] * linv[r];
    }
}

extern "C" void kernel_launch(void* const* d_in, const int* in_sizes, int n_in,
                              void* d_out, int out_size, void* d_ws, size_t ws_size,
                              hipStream_t stream) {
    (void)in_sizes; (void)n_in; (void)ws_size; (void)out_size;
    const float* x  = (const float*)d_in[0];
    // d_in[1] = index (int64) -- fixed equal-length sorted groups; unused.
    const float* Wq = (const float*)d_in[2];
    const float* bq = (const float*)d_in[3];
    const float* Wk = (const float*)d_in[4];
    const float* bk = (const float*)d_in[5];
    const float* Wv = (const float*)d_in[6];
    const float* bv = (const float*)d_in[7];
    float* out = (float*)d_out;

    short* Qw = (short*)d_ws;                       // [NTOK][64] bf16
    short* Kw = Qw + (size_t)NTOK * D_QK;           // [NTOK][64] bf16 (chunk-swizzled rows)
    short* Vt = Kw + (size_t)NTOK * D_QK;           // [GROUPS][16 tiles][128][64B] bf16

    short* Wt   = (short*)out;                      // scratch in d_out head
    float* bcat = (float*)((char*)out + 65536);

    prep_w<<<32, 256, 0, stream>>>(Wq, bq, Wk, bk, Wv, bv, Wt, bcat);
    proj_kernel<<<NTOK / 256, 256, 0, stream>>>(x, Wt, bcat, Qw, Kw, Vt);
    attn_kernel<<<dim3(GROUPS, 4), 256, 0, stream>>>(Qw, Kw, Vt, out);
}